// Round 2
// baseline (2231.730 us; speedup 1.0000x reference)
//
#include <hip/hip_runtime.h>

typedef unsigned short u16;
typedef __attribute__((ext_vector_type(8))) short short8;
typedef __attribute__((ext_vector_type(4))) float f32x4;

#define BB 4
#define SS 1024
#define HIDN 4096
#define HH 32
#define HKV 8
#define DD 128
#define RR 16
#define MM (BB * SS)

__device__ __forceinline__ u16 f2bf(float f) {
    unsigned u = __builtin_bit_cast(unsigned, f);
    unsigned r = u + 0x7FFFu + ((u >> 16) & 1u);
    return (u16)(r >> 16);
}
__device__ __forceinline__ float bf2f(u16 u) {
    unsigned v = ((unsigned)u) << 16;
    return __builtin_bit_cast(float, v);
}
__device__ __forceinline__ void glds16(const u16* g, u16* l) {
    __builtin_amdgcn_global_load_lds((const __attribute__((address_space(1))) unsigned int*)g,
                                     (__attribute__((address_space(3))) unsigned int*)l, 16, 0, 0);
}

// ---------- 1. fp32 -> bf16 cast ----------
__global__ void cast_kernel(const float* __restrict__ src, u16* __restrict__ dst, int n4) {
    int i = blockIdx.x * blockDim.x + threadIdx.x;
    int stride = gridDim.x * blockDim.x;
    for (; i < n4; i += stride) {
        float4 v = reinterpret_cast<const float4*>(src)[i];
        ushort4 o;
        o.x = f2bf(v.x); o.y = f2bf(v.y); o.z = f2bf(v.z); o.w = f2bf(v.w);
        reinterpret_cast<ushort4*>(dst)[i] = o;
    }
}

// ---------- 2. LoRA down-proj (q,k,v): 8 rows/block, 32 lanes/row share A reads ----------
__global__ __launch_bounds__(256) void lora_t3_kernel(
        const float* __restrict__ X,
        const float* __restrict__ Aq, const float* __restrict__ Ak, const float* __restrict__ Av,
        float* __restrict__ tq, float* __restrict__ tk, float* __restrict__ tv) {
    int rb = blockIdx.x * 8;
    int b = rb >> 10;
    int tid = threadIdx.x;
    int il = tid & 31;       // i-lane within row
    int rg = tid >> 5;       // row group 0..7
    int row = rb + rg;
    const float* Xr = X + (size_t)row * HIDN;
    const float* A0 = Aq + (size_t)b * RR * HIDN;
    const float* A1 = Ak + (size_t)b * RR * HIDN;
    const float* A2 = Av + (size_t)b * RR * HIDN;
    float acc[48];
#pragma unroll
    for (int j = 0; j < 48; j++) acc[j] = 0.f;
    for (int i = il; i < HIDN; i += 32) {
        float x = Xr[i];
#pragma unroll
        for (int r = 0; r < RR; r++) {
            acc[r]      += x * A0[(size_t)r * HIDN + i];
            acc[16 + r] += x * A1[(size_t)r * HIDN + i];
            acc[32 + r] += x * A2[(size_t)r * HIDN + i];
        }
    }
#pragma unroll
    for (int j = 0; j < 48; j++) {
        float v = acc[j];
#pragma unroll
        for (int off = 1; off < 32; off <<= 1) v += __shfl_xor(v, off, 64);
        acc[j] = v;
    }
    if (il == 0) {
#pragma unroll
        for (int r = 0; r < RR; r++) {
            tq[(size_t)row * RR + r] = acc[r];
            tk[(size_t)row * RR + r] = acc[16 + r];
            tv[(size_t)row * RR + r] = acc[32 + r];
        }
    }
}

// LoRA down-proj for O: bf16 input, 16 rows/block, 16 lanes/row
__global__ __launch_bounds__(256) void lora_t1_kernel(
        const u16* __restrict__ Xb, const float* __restrict__ Ao, float* __restrict__ to) {
    int rb = blockIdx.x * 16;
    int b = rb >> 10;
    int tid = threadIdx.x;
    int il = tid & 15;
    int rg = tid >> 4;
    int row = rb + rg;
    const u16* Xr = Xb + (size_t)row * HIDN;
    const float* Ab = Ao + (size_t)b * RR * HIDN;
    float acc[16];
#pragma unroll
    for (int j = 0; j < 16; j++) acc[j] = 0.f;
    for (int i = il; i < HIDN; i += 16) {
        float x = bf2f(Xr[i]);
#pragma unroll
        for (int r = 0; r < RR; r++) acc[r] += x * Ab[(size_t)r * HIDN + i];
    }
#pragma unroll
    for (int j = 0; j < 16; j++) {
        float v = acc[j];
#pragma unroll
        for (int off = 1; off < 16; off <<= 1) v += __shfl_xor(v, off, 64);
        acc[j] = v;
    }
    if (il == 0) {
#pragma unroll
        for (int r = 0; r < RR; r++) to[(size_t)row * RR + r] = acc[r];
    }
}

// ---------- 3. GEMM (m97 structure): 128x128 tile, BK=32, global_load_lds, XOR swizzle ----------
__global__ __launch_bounds__(256) void gemm_bt_lora(
        const u16* __restrict__ Xb, const u16* __restrict__ Wb,
        const float* __restrict__ T,  const float* __restrict__ Bl,
        void* __restrict__ outp, int N, int out_f32) {
    const int K = HIDN;
    __shared__ __attribute__((aligned(16))) u16 Als[128 * 32];
    __shared__ __attribute__((aligned(16))) u16 Bls[128 * 32];
    int tid = threadIdx.x;
    int wave = tid >> 6, lane = tid & 63;
    int quad = lane >> 4, l15 = lane & 15;
    int wm = wave >> 1, wn = wave & 1;
    int m0 = blockIdx.y * 128, n0 = blockIdx.x * 128;

    f32x4 acc[4][4] = {};
    // staging: lane covers row wave*32 + (lane>>2) (+16), slot lane&3.
    // XOR swizzle: slot p at row r stores logical chunk p ^ ((r>>1)&3)
    int arow = wave * 32 + (lane >> 2);
    int achunk = ((lane & 3) ^ ((lane >> 3) & 3)) * 8;   // (arow>>1)&3 == (lane>>3)&3
    const u16* gA0 = &Xb[(size_t)(m0 + arow) * K + achunk];
    const u16* gA1 = gA0 + (size_t)16 * K;
    const u16* gB0 = &Wb[(size_t)(n0 + arow) * K + achunk];
    const u16* gB1 = gB0 + (size_t)16 * K;
    u16* lA0 = &Als[wave * 32 * 32];
    u16* lA1 = &Als[(wave * 32 + 16) * 32];
    u16* lB0 = &Bls[wave * 32 * 32];
    u16* lB1 = &Bls[(wave * 32 + 16) * 32];
    int sel = ((l15 >> 1) & 3);   // read-side swizzle (row-base multiples of 8 drop out)

    for (int k0 = 0; k0 < K; k0 += 32) {
        glds16(gA0 + k0, lA0);
        glds16(gA1 + k0, lA1);
        glds16(gB0 + k0, lB0);
        glds16(gB1 + k0, lB1);
        __syncthreads();
        short8 af[4], bfr[4];
#pragma unroll
        for (int mi = 0; mi < 4; mi++)
            af[mi] = *(const short8*)&Als[(wm * 64 + mi * 16 + l15) * 32 + ((quad ^ sel) * 8)];
#pragma unroll
        for (int ni = 0; ni < 4; ni++)
            bfr[ni] = *(const short8*)&Bls[(wn * 64 + ni * 16 + l15) * 32 + ((quad ^ sel) * 8)];
#pragma unroll
        for (int mi = 0; mi < 4; mi++)
#pragma unroll
            for (int ni = 0; ni < 4; ni++)
                acc[mi][ni] = __builtin_amdgcn_mfma_f32_16x16x32_bf16(af[mi], bfr[ni], acc[mi][ni], 0, 0, 0);
        __syncthreads();
    }

    int bidx = m0 >> 10;
    const float* BlB = Bl + (size_t)bidx * N * RR;
#pragma unroll
    for (int mi = 0; mi < 4; mi++) {
#pragma unroll
        for (int r = 0; r < 4; r++) {
            int row = m0 + wm * 64 + mi * 16 + quad * 4 + r;
            const float4* Tr4 = (const float4*)&T[(size_t)row * RR];
            float4 t4[4];
#pragma unroll
            for (int p = 0; p < 4; p++) t4[p] = Tr4[p];
#pragma unroll
            for (int ni = 0; ni < 4; ni++) {
                int col = n0 + wn * 64 + ni * 16 + l15;
                const float4* Bc4 = (const float4*)&BlB[(size_t)col * RR];
                float add = 0.f;
#pragma unroll
                for (int p = 0; p < 4; p++) {
                    float4 b4 = Bc4[p];
                    add += t4[p].x * b4.x + t4[p].y * b4.y + t4[p].z * b4.z + t4[p].w * b4.w;
                }
                float v = acc[mi][ni][r] + add;
                if (out_f32) ((float*)outp)[(size_t)row * N + col] = v;
                else         ((u16*)outp)[(size_t)row * N + col]  = f2bf(v);
            }
        }
    }
}

// ---------- 4. RoPE in place ----------
__global__ void rope_kernel(u16* __restrict__ x, int nh) {
    int idx = blockIdx.x * 256 + threadIdx.x;
    int total = BB * SS * nh * (DD / 2);
    if (idx >= total) return;
    int d = idx & 63;
    int t = idx >> 6;
    int pos = (t / nh) & (SS - 1);
    size_t base = (size_t)t * DD;
    float inv = __expf(-(float)d * (9.210340371976184f / 64.0f));
    float ang = (float)pos * inv;
    float c = cosf(ang), s = sinf(ang);
    float x1 = bf2f(x[base + d]);
    float x2 = bf2f(x[base + 64 + d]);
    x[base + d]      = f2bf(x1 * c - x2 * s);
    x[base + 64 + d] = f2bf(x2 * c + x1 * s);
}

// ---------- 5. flash attention: BQ=128 (4 waves, m-tiles {w,w+4}), BK=64, V transposed ----------
#define KLD 136    // K tile stride (u16): dword stride 68 == 4 mod 32 -> 2-way reads
#define VTLD 72    // V^T tile stride: dword 36 == 4 mod 32 -> 2-way reads
#define PLD 72
__global__ __launch_bounds__(256) void flash_kernel(
        const u16* __restrict__ Q, const u16* __restrict__ Kx, const u16* __restrict__ V,
        u16* __restrict__ Oa) {
    __shared__ __attribute__((aligned(16))) u16 Kls[64 * KLD];
    __shared__ __attribute__((aligned(16))) u16 Vt[128 * VTLD];
    __shared__ __attribute__((aligned(16))) u16 Pls[4 * 32 * PLD];
    int tid = threadIdx.x;
    int wave = tid >> 6, lane = tid & 63;
    int quad = lane >> 4, l15 = lane & 15;
    int blk = blockIdx.x;
    int qt = 7 - (blk >> 7);       // heavy q-tiles dispatch first
    int h  = blk & 31;
    int b  = (blk >> 5) & 3;
    int hkv = h >> 2;
    int q0 = qt * 128;
    const float scale = 0.08838834764831845f;

    // Q fragments for m-tiles wave and wave+4
    short8 qf[2][4];
#pragma unroll
    for (int mi = 0; mi < 2; mi++) {
        int qrow = q0 + (wave + 4 * mi) * 16 + l15;
        const u16* qp = Q + ((size_t)(b * SS + qrow) * HH + h) * DD;
#pragma unroll
        for (int kt = 0; kt < 4; kt++) qf[mi][kt] = *(const short8*)&qp[kt * 32 + quad * 8];
    }

    f32x4 oacc[2][8] = {};
    float mrow[2][4], lrow[2][4];
#pragma unroll
    for (int mi = 0; mi < 2; mi++)
#pragma unroll
        for (int r = 0; r < 4; r++) { mrow[mi][r] = -3.0e38f; lrow[mi][r] = 0.f; }

    int krow = tid >> 2;            // K staging: row 0..63
    int kc   = (tid & 3) * 32;      // 4 chunks of 8
    int vp   = tid >> 3;            // V staging: row-pair 0..31
    int vc   = (tid & 7) * 16;      // 2 chunks of 8

    int nkb = (q0 >> 6) + 2;
    for (int ib = 0; ib < nkb; ib++) {
        int kb = ib * 64;
        // stage K row-major
        const u16* kg = Kx + ((size_t)(b * SS + kb + krow) * HKV + hkv) * DD + kc;
#pragma unroll
        for (int j = 0; j < 4; j++)
            *(uint4*)&Kls[krow * KLD + kc + j * 8] = *(const uint4*)&kg[j * 8];
        // stage V transposed: Vt[d][k], pack row-pairs into b32 writes
        const u16* vg0 = V + ((size_t)(b * SS + kb + 2 * vp) * HKV + hkv) * DD + vc;
        const u16* vg1 = vg0 + HKV * DD;
#pragma unroll
        for (int j = 0; j < 2; j++) {
            uint4 a4 = *(const uint4*)&vg0[j * 8];
            uint4 b4 = *(const uint4*)&vg1[j * 8];
            const u16* ap = (const u16*)&a4;
            const u16* bp = (const u16*)&b4;
#pragma unroll
            for (int e = 0; e < 8; e++) {
                unsigned pk = (unsigned)ap[e] | ((unsigned)bp[e] << 16);
                *(unsigned*)&Vt[(size_t)(vc + j * 8 + e) * VTLD + 2 * vp] = pk;
            }
        }
        __syncthreads();

        // QK^T: S[2 m-tiles][64 cols]
        f32x4 sa[2][4] = {};
#pragma unroll
        for (int nt = 0; nt < 4; nt++) {
            short8 kf[4];
#pragma unroll
            for (int kt = 0; kt < 4; kt++)
                kf[kt] = *(const short8*)&Kls[(nt * 16 + l15) * KLD + kt * 32 + quad * 8];
#pragma unroll
            for (int mi = 0; mi < 2; mi++)
#pragma unroll
                for (int kt = 0; kt < 4; kt++)
                    sa[mi][nt] = __builtin_amdgcn_mfma_f32_16x16x32_bf16(qf[mi][kt], kf[kt], sa[mi][nt], 0, 0, 0);
        }

        // online softmax + P store (bf16, A-operand layout target)
#pragma unroll
        for (int mi = 0; mi < 2; mi++) {
#pragma unroll
            for (int r = 0; r < 4; r++) {
                int qpos = q0 + (wave + 4 * mi) * 16 + quad * 4 + r;
                float s[4];
#pragma unroll
                for (int nt = 0; nt < 4; nt++) {
                    float v = sa[mi][nt][r] * scale;
                    int kpos = kb + nt * 16 + l15;
                    s[nt] = (kpos > qpos) ? -3.0e38f : v;
                }
                float mx = fmaxf(fmaxf(s[0], s[1]), fmaxf(s[2], s[3]));
#pragma unroll
                for (int off = 1; off < 16; off <<= 1) mx = fmaxf(mx, __shfl_xor(mx, off, 64));
                float mnew = fmaxf(mrow[mi][r], mx);
                float alpha = __expf(mrow[mi][r] - mnew);
                mrow[mi][r] = mnew;
                float sum = 0.f;
#pragma unroll
                for (int nt = 0; nt < 4; nt++) {
                    float e = __expf(s[nt] - mnew);
                    sum += e;
                    Pls[wave * (32 * PLD) + (mi * 16 + quad * 4 + r) * PLD + nt * 16 + l15] = f2bf(e);
                }
#pragma unroll
                for (int off = 1; off < 16; off <<= 1) sum += __shfl_xor(sum, off, 64);
                lrow[mi][r] = lrow[mi][r] * alpha + sum;
#pragma unroll
                for (int dt = 0; dt < 8; dt++) oacc[mi][dt][r] *= alpha;
            }
        }
        __syncthreads();   // P visible to own wave only, but barrier also guards Vt reuse

        // PV: O[2][128] += P[2x16x64] * V[64x128]
#pragma unroll
        for (int kt = 0; kt < 2; kt++) {
            short8 pf[2];
#pragma unroll
            for (int mi = 0; mi < 2; mi++)
                pf[mi] = *(const short8*)&Pls[wave * (32 * PLD) + (mi * 16 + l15) * PLD + kt * 32 + quad * 8];
#pragma unroll
            for (int dt = 0; dt < 8; dt++) {
                short8 vf = *(const short8*)&Vt[(size_t)(dt * 16 + l15) * VTLD + kt * 32 + quad * 8];
#pragma unroll
                for (int mi = 0; mi < 2; mi++)
                    oacc[mi][dt] = __builtin_amdgcn_mfma_f32_16x16x32_bf16(pf[mi], vf, oacc[mi][dt], 0, 0, 0);
            }
        }
        __syncthreads();
    }

#pragma unroll
    for (int mi = 0; mi < 2; mi++)
#pragma unroll
        for (int r = 0; r < 4; r++) {
            float inv = 1.0f / lrow[mi][r];
            int orow = q0 + (wave + 4 * mi) * 16 + quad * 4 + r;
            u16* op = Oa + ((size_t)(b * SS + orow) * HH + h) * DD;
#pragma unroll
            for (int dt = 0; dt < 8; dt++)
                op[dt * 16 + l15] = f2bf(oacc[mi][dt][r] * inv);
        }
}

// ---------- launch ----------
extern "C" void kernel_launch(void* const* d_in, const int* in_sizes, int n_in,
                              void* d_out, int out_size, void* d_ws, size_t ws_size,
                              hipStream_t stream) {
    const float* X  = (const float*)d_in[0];
    const float* Wq = (const float*)d_in[1];
    const float* Wk = (const float*)d_in[2];
    const float* Wv = (const float*)d_in[3];
    const float* Wo = (const float*)d_in[4];
    const float* Aq = (const float*)d_in[5];
    const float* Bq = (const float*)d_in[6];
    const float* Ak = (const float*)d_in[7];
    const float* Bk = (const float*)d_in[8];
    const float* Av = (const float*)d_in[9];
    const float* Bv = (const float*)d_in[10];
    const float* Ao = (const float*)d_in[11];
    const float* Bo = (const float*)d_in[12];

    char* w = (char*)d_ws;
    auto take = [&](size_t bytes) {
        char* p = w;
        w += (bytes + 255) & ~(size_t)255;
        return p;
    };
    u16*   Xb  = (u16*)  take((size_t)MM * HIDN * 2);
    u16*   Wqb = (u16*)  take((size_t)HIDN * HIDN * 2);
    u16*   Wkb = (u16*)  take((size_t)1024 * HIDN * 2);
    u16*   Wvb = (u16*)  take((size_t)1024 * HIDN * 2);
    u16*   Wob = (u16*)  take((size_t)HIDN * HIDN * 2);
    float* tq  = (float*)take((size_t)MM * RR * 4);
    float* tk  = (float*)take((size_t)MM * RR * 4);
    float* tv  = (float*)take((size_t)MM * RR * 4);
    float* to  = (float*)take((size_t)MM * RR * 4);
    u16*   qb  = (u16*)  take((size_t)MM * HIDN * 2);
    u16*   kbuf= (u16*)  take((size_t)MM * 1024 * 2);
    u16*   vbuf= (u16*)  take((size_t)MM * 1024 * 2);
    u16*   attn = Xb;   // Xb dead after V GEMM

    cast_kernel<<<2048, 256, 0, stream>>>(X,  Xb,  MM * HIDN / 4);
    cast_kernel<<<2048, 256, 0, stream>>>(Wq, Wqb, HIDN * HIDN / 4);
    cast_kernel<<<1024, 256, 0, stream>>>(Wk, Wkb, 1024 * HIDN / 4);
    cast_kernel<<<1024, 256, 0, stream>>>(Wv, Wvb, 1024 * HIDN / 4);
    cast_kernel<<<2048, 256, 0, stream>>>(Wo, Wob, HIDN * HIDN / 4);
    lora_t3_kernel<<<MM / 8, 256, 0, stream>>>(X, Aq, Ak, Av, tq, tk, tv);
    gemm_bt_lora<<<dim3(32, 32), 256, 0, stream>>>(Xb, Wqb, tq, Bq, qb,   HIDN, 0);
    gemm_bt_lora<<<dim3(8,  32), 256, 0, stream>>>(Xb, Wkb, tk, Bk, kbuf, 1024, 0);
    gemm_bt_lora<<<dim3(8,  32), 256, 0, stream>>>(Xb, Wvb, tv, Bv, vbuf, 1024, 0);
    rope_kernel<<<BB * SS * HH * 64 / 256, 256, 0, stream>>>(qb, HH);
    rope_kernel<<<BB * SS * HKV * 64 / 256, 256, 0, stream>>>(kbuf, HKV);
    flash_kernel<<<BB * HH * (SS / 128), 256, 0, stream>>>(qb, kbuf, vbuf, attn);
    lora_t1_kernel<<<MM / 16, 256, 0, stream>>>(attn, Ao, to);
    gemm_bt_lora<<<dim3(32, 32), 256, 0, stream>>>(attn, Wob, to, Bo, (void*)d_out, HIDN, 1);
}

// Round 3
// 998.226 us; speedup vs baseline: 2.2357x; 2.2357x over previous
//
#include <hip/hip_runtime.h>

typedef unsigned short u16;
typedef __attribute__((ext_vector_type(8))) short short8;
typedef __attribute__((ext_vector_type(4))) float f32x4;

#define BB 4
#define SS 1024
#define HIDN 4096
#define HH 32
#define HKV 8
#define DD 128
#define RR 16
#define MM (BB * SS)

__device__ __forceinline__ u16 f2bf(float f) {
    unsigned u = __builtin_bit_cast(unsigned, f);
    unsigned r = u + 0x7FFFu + ((u >> 16) & 1u);
    return (u16)(r >> 16);
}
__device__ __forceinline__ float bf2f(u16 u) {
    unsigned v = ((unsigned)u) << 16;
    return __builtin_bit_cast(float, v);
}
__device__ __forceinline__ void glds16(const u16* g, u16* l) {
    __builtin_amdgcn_global_load_lds((const __attribute__((address_space(1))) unsigned int*)g,
                                     (__attribute__((address_space(3))) unsigned int*)l, 16, 0, 0);
}

// ---------- 0. zero-fill (ws is poisoned 0xAA) ----------
__global__ void zero_kernel(float* __restrict__ p, int n) {
    int i = blockIdx.x * blockDim.x + threadIdx.x;
    if (i < n) p[i] = 0.f;
}

// ---------- 1. fp32 -> bf16 cast ----------
__global__ void cast_kernel(const float* __restrict__ src, u16* __restrict__ dst, int n4) {
    int i = blockIdx.x * blockDim.x + threadIdx.x;
    int stride = gridDim.x * blockDim.x;
    for (; i < n4; i += stride) {
        float4 v = reinterpret_cast<const float4*>(src)[i];
        ushort4 o;
        o.x = f2bf(v.x); o.y = f2bf(v.y); o.z = f2bf(v.z); o.w = f2bf(v.w);
        reinterpret_cast<ushort4*>(dst)[i] = o;
    }
}

// cast LoRA-A [B][16][HID] fp32 -> slice of Acat [B][48][HID] bf16
__global__ void cast_lora_a(const float* __restrict__ src, u16* __restrict__ dst,
                            int perB4, int dstStrideU16, int n4) {
    int i = blockIdx.x * blockDim.x + threadIdx.x;
    int stride = gridDim.x * blockDim.x;
    for (; i < n4; i += stride) {
        int b = i / perB4;
        int w4 = i - b * perB4;
        float4 v = reinterpret_cast<const float4*>(src)[i];
        ushort4 o;
        o.x = f2bf(v.x); o.y = f2bf(v.y); o.z = f2bf(v.z); o.w = f2bf(v.w);
        reinterpret_cast<ushort4*>(dst + (size_t)b * dstStrideU16)[w4] = o;
    }
}

// ---------- 2. LoRA down-proj via MFMA: T[M][NT*16] = Xb[M][K] * Ab[b][NT*16][K]^T ----------
// grid (4 k-chunks, 32 m-tiles), split-K with fp32 atomicAdd into pre-zeroed T
template <int NT>
__global__ __launch_bounds__(256) void lora_mfma(
        const u16* __restrict__ Xb, const u16* __restrict__ Ab, float* __restrict__ T) {
    const int N = NT * 16;
    __shared__ __attribute__((aligned(16))) u16 Xls[128 * 32];
    __shared__ __attribute__((aligned(16))) u16 Als[NT * 16 * 32];
    int tid = threadIdx.x;
    int wave = tid >> 6, lane = tid & 63;
    int quad = lane >> 4, l15 = lane & 15;
    int m0 = blockIdx.y * 128;
    int b = m0 >> 10;
    int k0base = blockIdx.x * (HIDN / 4);
    const u16* Abb = Ab + (size_t)b * N * HIDN;
    f32x4 acc[2][NT] = {};
    int r0 = tid >> 2;
    int c0 = (tid & 3) * 8;
    for (int k0 = k0base; k0 < k0base + HIDN / 4; k0 += 32) {
        *(uint4*)&Xls[r0 * 32 + c0]        = *(const uint4*)&Xb[(size_t)(m0 + r0) * HIDN + k0 + c0];
        *(uint4*)&Xls[(r0 + 64) * 32 + c0] = *(const uint4*)&Xb[(size_t)(m0 + r0 + 64) * HIDN + k0 + c0];
        if (tid < NT * 16 * 4)
            *(uint4*)&Als[r0 * 32 + c0] = *(const uint4*)&Abb[(size_t)r0 * HIDN + k0 + c0];
        __syncthreads();
        short8 xf[2], af[NT];
#pragma unroll
        for (int mi = 0; mi < 2; mi++)
            xf[mi] = *(const short8*)&Xls[(wave * 32 + mi * 16 + l15) * 32 + quad * 8];
#pragma unroll
        for (int nt = 0; nt < NT; nt++)
            af[nt] = *(const short8*)&Als[(nt * 16 + l15) * 32 + quad * 8];
#pragma unroll
        for (int mi = 0; mi < 2; mi++)
#pragma unroll
            for (int nt = 0; nt < NT; nt++)
                acc[mi][nt] = __builtin_amdgcn_mfma_f32_16x16x32_bf16(xf[mi], af[nt], acc[mi][nt], 0, 0, 0);
        __syncthreads();
    }
#pragma unroll
    for (int mi = 0; mi < 2; mi++)
#pragma unroll
        for (int nt = 0; nt < NT; nt++)
#pragma unroll
            for (int r = 0; r < 4; r++) {
                int row = m0 + wave * 32 + mi * 16 + quad * 4 + r;
                atomicAdd(&T[(size_t)row * N + nt * 16 + l15], acc[mi][nt][r]);
            }
}

// ---------- 3. GEMM (m97 structure): 128x128 tile, BK=32, global_load_lds, XOR swizzle ----------
__global__ __launch_bounds__(256) void gemm_bt_lora(
        const u16* __restrict__ Xb, const u16* __restrict__ Wb,
        const float* __restrict__ T, int ts, const float* __restrict__ Bl,
        void* __restrict__ outp, int N, int out_f32) {
    const int K = HIDN;
    __shared__ __attribute__((aligned(16))) u16 Als[128 * 32];
    __shared__ __attribute__((aligned(16))) u16 Bls[128 * 32];
    int tid = threadIdx.x;
    int wave = tid >> 6, lane = tid & 63;
    int quad = lane >> 4, l15 = lane & 15;
    int wm = wave >> 1, wn = wave & 1;
    int m0 = blockIdx.y * 128, n0 = blockIdx.x * 128;

    f32x4 acc[4][4] = {};
    int arow = wave * 32 + (lane >> 2);
    int achunk = ((lane & 3) ^ ((lane >> 3) & 3)) * 8;
    const u16* gA0 = &Xb[(size_t)(m0 + arow) * K + achunk];
    const u16* gA1 = gA0 + (size_t)16 * K;
    const u16* gB0 = &Wb[(size_t)(n0 + arow) * K + achunk];
    const u16* gB1 = gB0 + (size_t)16 * K;
    u16* lA0 = &Als[wave * 32 * 32];
    u16* lA1 = &Als[(wave * 32 + 16) * 32];
    u16* lB0 = &Bls[wave * 32 * 32];
    u16* lB1 = &Bls[(wave * 32 + 16) * 32];
    int sel = ((l15 >> 1) & 3);

    for (int k0 = 0; k0 < K; k0 += 32) {
        glds16(gA0 + k0, lA0);
        glds16(gA1 + k0, lA1);
        glds16(gB0 + k0, lB0);
        glds16(gB1 + k0, lB1);
        __syncthreads();
        short8 af[4], bfr[4];
#pragma unroll
        for (int mi = 0; mi < 4; mi++)
            af[mi] = *(const short8*)&Als[(wm * 64 + mi * 16 + l15) * 32 + ((quad ^ sel) * 8)];
#pragma unroll
        for (int ni = 0; ni < 4; ni++)
            bfr[ni] = *(const short8*)&Bls[(wn * 64 + ni * 16 + l15) * 32 + ((quad ^ sel) * 8)];
#pragma unroll
        for (int mi = 0; mi < 4; mi++)
#pragma unroll
            for (int ni = 0; ni < 4; ni++)
                acc[mi][ni] = __builtin_amdgcn_mfma_f32_16x16x32_bf16(af[mi], bfr[ni], acc[mi][ni], 0, 0, 0);
        __syncthreads();
    }

    int bidx = m0 >> 10;
    const float* BlB = Bl + (size_t)bidx * N * RR;
#pragma unroll
    for (int mi = 0; mi < 4; mi++) {
#pragma unroll
        for (int r = 0; r < 4; r++) {
            int row = m0 + wm * 64 + mi * 16 + quad * 4 + r;
            const float4* Tr4 = (const float4*)&T[(size_t)row * ts];
            float4 t4[4];
#pragma unroll
            for (int p = 0; p < 4; p++) t4[p] = Tr4[p];
#pragma unroll
            for (int ni = 0; ni < 4; ni++) {
                int col = n0 + wn * 64 + ni * 16 + l15;
                const float4* Bc4 = (const float4*)&BlB[(size_t)col * RR];
                float add = 0.f;
#pragma unroll
                for (int p = 0; p < 4; p++) {
                    float4 b4 = Bc4[p];
                    add += t4[p].x * b4.x + t4[p].y * b4.y + t4[p].z * b4.z + t4[p].w * b4.w;
                }
                float v = acc[mi][ni][r] + add;
                if (out_f32) ((float*)outp)[(size_t)row * N + col] = v;
                else         ((u16*)outp)[(size_t)row * N + col]  = f2bf(v);
            }
        }
    }
}

// ---------- 4. RoPE in place ----------
__global__ void rope_kernel(u16* __restrict__ x, int nh) {
    int idx = blockIdx.x * 256 + threadIdx.x;
    int total = BB * SS * nh * (DD / 2);
    if (idx >= total) return;
    int d = idx & 63;
    int t = idx >> 6;
    int pos = (t / nh) & (SS - 1);
    size_t base = (size_t)t * DD;
    float inv = __expf(-(float)d * (9.210340371976184f / 64.0f));
    float ang = (float)pos * inv;
    float c = cosf(ang), s = sinf(ang);
    float x1 = bf2f(x[base + d]);
    float x2 = bf2f(x[base + 64 + d]);
    x[base + d]      = f2bf(x1 * c - x2 * s);
    x[base + 64 + d] = f2bf(x2 * c + x1 * s);
}

// ---------- 5. flash attention: BQ=128 (4 waves, m-tiles {w,w+4}), BK=64, V transposed ----------
#define KLD 136
#define VTLD 72
#define PLD 72
__global__ __launch_bounds__(256) void flash_kernel(
        const u16* __restrict__ Q, const u16* __restrict__ Kx, const u16* __restrict__ V,
        u16* __restrict__ Oa) {
    __shared__ __attribute__((aligned(16))) u16 Kls[64 * KLD];
    __shared__ __attribute__((aligned(16))) u16 Vt[128 * VTLD];
    __shared__ __attribute__((aligned(16))) u16 Pls[4 * 32 * PLD];
    int tid = threadIdx.x;
    int wave = tid >> 6, lane = tid & 63;
    int quad = lane >> 4, l15 = lane & 15;
    int blk = blockIdx.x;
    int qt = 7 - (blk >> 7);
    int h  = blk & 31;
    int b  = (blk >> 5) & 3;
    int hkv = h >> 2;
    int q0 = qt * 128;
    const float scale = 0.08838834764831845f;

    short8 qf[2][4];
#pragma unroll
    for (int mi = 0; mi < 2; mi++) {
        int qrow = q0 + (wave + 4 * mi) * 16 + l15;
        const u16* qp = Q + ((size_t)(b * SS + qrow) * HH + h) * DD;
#pragma unroll
        for (int kt = 0; kt < 4; kt++) qf[mi][kt] = *(const short8*)&qp[kt * 32 + quad * 8];
    }

    f32x4 oacc[2][8] = {};
    float mrow[2][4], lrow[2][4];
#pragma unroll
    for (int mi = 0; mi < 2; mi++)
#pragma unroll
        for (int r = 0; r < 4; r++) { mrow[mi][r] = -3.0e38f; lrow[mi][r] = 0.f; }

    int krow = tid >> 2;
    int kc   = (tid & 3) * 32;
    int vp   = tid >> 3;
    int vc   = (tid & 7) * 16;

    int nkb = (q0 >> 6) + 2;
    for (int ib = 0; ib < nkb; ib++) {
        int kb = ib * 64;
        const u16* kg = Kx + ((size_t)(b * SS + kb + krow) * HKV + hkv) * DD + kc;
#pragma unroll
        for (int j = 0; j < 4; j++)
            *(uint4*)&Kls[krow * KLD + kc + j * 8] = *(const uint4*)&kg[j * 8];
        const u16* vg0 = V + ((size_t)(b * SS + kb + 2 * vp) * HKV + hkv) * DD + vc;
        const u16* vg1 = vg0 + HKV * DD;
#pragma unroll
        for (int j = 0; j < 2; j++) {
            uint4 a4 = *(const uint4*)&vg0[j * 8];
            uint4 b4 = *(const uint4*)&vg1[j * 8];
            const u16* ap = (const u16*)&a4;
            const u16* bp = (const u16*)&b4;
#pragma unroll
            for (int e = 0; e < 8; e++) {
                unsigned pk = (unsigned)ap[e] | ((unsigned)bp[e] << 16);
                *(unsigned*)&Vt[(size_t)(vc + j * 8 + e) * VTLD + 2 * vp] = pk;
            }
        }
        __syncthreads();

        f32x4 sa[2][4] = {};
#pragma unroll
        for (int nt = 0; nt < 4; nt++) {
            short8 kf[4];
#pragma unroll
            for (int kt = 0; kt < 4; kt++)
                kf[kt] = *(const short8*)&Kls[(nt * 16 + l15) * KLD + kt * 32 + quad * 8];
#pragma unroll
            for (int mi = 0; mi < 2; mi++)
#pragma unroll
                for (int kt = 0; kt < 4; kt++)
                    sa[mi][nt] = __builtin_amdgcn_mfma_f32_16x16x32_bf16(qf[mi][kt], kf[kt], sa[mi][nt], 0, 0, 0);
        }

#pragma unroll
        for (int mi = 0; mi < 2; mi++) {
#pragma unroll
            for (int r = 0; r < 4; r++) {
                int qpos = q0 + (wave + 4 * mi) * 16 + quad * 4 + r;
                float s[4];
#pragma unroll
                for (int nt = 0; nt < 4; nt++) {
                    float v = sa[mi][nt][r] * scale;
                    int kpos = kb + nt * 16 + l15;
                    s[nt] = (kpos > qpos) ? -3.0e38f : v;
                }
                float mx = fmaxf(fmaxf(s[0], s[1]), fmaxf(s[2], s[3]));
#pragma unroll
                for (int off = 1; off < 16; off <<= 1) mx = fmaxf(mx, __shfl_xor(mx, off, 64));
                float mnew = fmaxf(mrow[mi][r], mx);
                float alpha = __expf(mrow[mi][r] - mnew);
                mrow[mi][r] = mnew;
                float sum = 0.f;
#pragma unroll
                for (int nt = 0; nt < 4; nt++) {
                    float e = __expf(s[nt] - mnew);
                    sum += e;
                    Pls[wave * (32 * PLD) + (mi * 16 + quad * 4 + r) * PLD + nt * 16 + l15] = f2bf(e);
                }
#pragma unroll
                for (int off = 1; off < 16; off <<= 1) sum += __shfl_xor(sum, off, 64);
                lrow[mi][r] = lrow[mi][r] * alpha + sum;
#pragma unroll
                for (int dt = 0; dt < 8; dt++) oacc[mi][dt][r] *= alpha;
            }
        }
        __syncthreads();

#pragma unroll
        for (int kt = 0; kt < 2; kt++) {
            short8 pf[2];
#pragma unroll
            for (int mi = 0; mi < 2; mi++)
                pf[mi] = *(const short8*)&Pls[wave * (32 * PLD) + (mi * 16 + l15) * PLD + kt * 32 + quad * 8];
#pragma unroll
            for (int dt = 0; dt < 8; dt++) {
                short8 vf = *(const short8*)&Vt[(size_t)(dt * 16 + l15) * VTLD + kt * 32 + quad * 8];
#pragma unroll
                for (int mi = 0; mi < 2; mi++)
                    oacc[mi][dt] = __builtin_amdgcn_mfma_f32_16x16x32_bf16(pf[mi], vf, oacc[mi][dt], 0, 0, 0);
            }
        }
        __syncthreads();
    }

#pragma unroll
    for (int mi = 0; mi < 2; mi++)
#pragma unroll
        for (int r = 0; r < 4; r++) {
            float inv = 1.0f / lrow[mi][r];
            int orow = q0 + (wave + 4 * mi) * 16 + quad * 4 + r;
            u16* op = Oa + ((size_t)(b * SS + orow) * HH + h) * DD;
#pragma unroll
            for (int dt = 0; dt < 8; dt++)
                op[dt * 16 + l15] = f2bf(oacc[mi][dt][r] * inv);
        }
}

// ---------- launch ----------
extern "C" void kernel_launch(void* const* d_in, const int* in_sizes, int n_in,
                              void* d_out, int out_size, void* d_ws, size_t ws_size,
                              hipStream_t stream) {
    const float* X  = (const float*)d_in[0];
    const float* Wq = (const float*)d_in[1];
    const float* Wk = (const float*)d_in[2];
    const float* Wv = (const float*)d_in[3];
    const float* Wo = (const float*)d_in[4];
    const float* Aq = (const float*)d_in[5];
    const float* Bq = (const float*)d_in[6];
    const float* Ak = (const float*)d_in[7];
    const float* Bk = (const float*)d_in[8];
    const float* Av = (const float*)d_in[9];
    const float* Bv = (const float*)d_in[10];
    const float* Ao = (const float*)d_in[11];
    const float* Bo = (const float*)d_in[12];

    char* w = (char*)d_ws;
    auto take = [&](size_t bytes) {
        char* p = w;
        w += (bytes + 255) & ~(size_t)255;
        return p;
    };
    u16*   Xb  = (u16*)  take((size_t)MM * HIDN * 2);
    u16*   Wqb = (u16*)  take((size_t)HIDN * HIDN * 2);
    u16*   Wkb = (u16*)  take((size_t)1024 * HIDN * 2);
    u16*   Wvb = (u16*)  take((size_t)1024 * HIDN * 2);
    u16*   Wob = (u16*)  take((size_t)HIDN * HIDN * 2);
    float* Tcat= (float*)take((size_t)MM * 48 * 4);          // q|k|v lora-down, [M][48]
    float* To  = (float*)take((size_t)MM * 16 * 4);          // o lora-down, [M][16]
    u16*   Acat= (u16*)  take((size_t)BB * 48 * HIDN * 2);   // bf16 [B][48][HID]
    u16*   Aob = (u16*)  take((size_t)BB * 16 * HIDN * 2);   // bf16 [B][16][HID]
    u16*   qb  = (u16*)  take((size_t)MM * HIDN * 2);
    u16*   kbuf= (u16*)  take((size_t)MM * 1024 * 2);
    u16*   vbuf= (u16*)  take((size_t)MM * 1024 * 2);
    u16*   attn = Xb;   // Xb dead after V GEMM

    // zero split-K accumulators (Tcat and To are adjacent after 256B-align: both sizes are 256B multiples)
    zero_kernel<<<(MM * 64 + 255) / 256, 256, 0, stream>>>(Tcat, MM * 64);

    // casts
    cast_kernel<<<2048, 256, 0, stream>>>(X,  Xb,  MM * HIDN / 4);
    cast_kernel<<<2048, 256, 0, stream>>>(Wq, Wqb, HIDN * HIDN / 4);
    cast_kernel<<<1024, 256, 0, stream>>>(Wk, Wkb, 1024 * HIDN / 4);
    cast_kernel<<<1024, 256, 0, stream>>>(Wv, Wvb, 1024 * HIDN / 4);
    cast_kernel<<<2048, 256, 0, stream>>>(Wo, Wob, HIDN * HIDN / 4);
    {
        const int perB4 = 16 * HIDN / 4;          // 16384
        const int n4 = BB * perB4;
        cast_lora_a<<<256, 256, 0, stream>>>(Aq, Acat,             perB4, 48 * HIDN, n4);
        cast_lora_a<<<256, 256, 0, stream>>>(Ak, Acat + 16 * HIDN, perB4, 48 * HIDN, n4);
        cast_lora_a<<<256, 256, 0, stream>>>(Av, Acat + 32 * HIDN, perB4, 48 * HIDN, n4);
        cast_kernel<<<256, 256, 0, stream>>>(Ao, Aob, BB * 16 * HIDN / 4);
    }

    // LoRA down-proj (q,k,v) via MFMA split-K
    lora_mfma<3><<<dim3(4, 32), 256, 0, stream>>>(Xb, Acat, Tcat);

    // projections (bf16 out, LoRA fused)
    gemm_bt_lora<<<dim3(32, 32), 256, 0, stream>>>(Xb, Wqb, Tcat,      48, Bq, qb,   HIDN, 0);
    gemm_bt_lora<<<dim3(8,  32), 256, 0, stream>>>(Xb, Wkb, Tcat + 16, 48, Bk, kbuf, 1024, 0);
    gemm_bt_lora<<<dim3(8,  32), 256, 0, stream>>>(Xb, Wvb, Tcat + 32, 48, Bv, vbuf, 1024, 0);
    rope_kernel<<<BB * SS * HH * 64 / 256, 256, 0, stream>>>(qb, HH);
    rope_kernel<<<BB * SS * HKV * 64 / 256, 256, 0, stream>>>(kbuf, HKV);
    flash_kernel<<<BB * HH * (SS / 128), 256, 0, stream>>>(qb, kbuf, vbuf, attn);

    // LoRA down-proj (O) via MFMA split-K, then O GEMM -> fp32 out
    lora_mfma<1><<<dim3(4, 32), 256, 0, stream>>>(attn, Aob, To);
    gemm_bt_lora<<<dim3(32, 32), 256, 0, stream>>>(attn, Wob, To, 16, Bo, (void*)d_out, HIDN, 1);
}

// Round 4
// 904.171 us; speedup vs baseline: 2.4683x; 1.1040x over previous
//
#include <hip/hip_runtime.h>

typedef unsigned short u16;
typedef __attribute__((ext_vector_type(8))) short short8;
typedef __attribute__((ext_vector_type(4))) float f32x4;

#define BB 4
#define SS 1024
#define HIDN 4096
#define HH 32
#define HKV 8
#define DD 128
#define RR 16
#define MM (BB * SS)
#define NQKV 6144   // 4096 q | 1024 k | 1024 v

__device__ __forceinline__ u16 f2bf(float f) {
    unsigned u = __builtin_bit_cast(unsigned, f);
    unsigned r = u + 0x7FFFu + ((u >> 16) & 1u);
    return (u16)(r >> 16);
}
__device__ __forceinline__ float bf2f(u16 u) {
    unsigned v = ((unsigned)u) << 16;
    return __builtin_bit_cast(float, v);
}
__device__ __forceinline__ void glds16(const u16* g, u16* l) {
    __builtin_amdgcn_global_load_lds((const __attribute__((address_space(1))) unsigned int*)g,
                                     (__attribute__((address_space(3))) unsigned int*)l, 16, 0, 0);
}

// ---------- 0. zero-fill ----------
__global__ void zero_kernel(float* __restrict__ p, int n) {
    int i = blockIdx.x * blockDim.x + threadIdx.x;
    if (i < n) p[i] = 0.f;
}

// ---------- 1. fp32 -> bf16 cast ----------
__global__ void cast_kernel(const float* __restrict__ src, u16* __restrict__ dst, int n4) {
    int i = blockIdx.x * blockDim.x + threadIdx.x;
    int stride = gridDim.x * blockDim.x;
    for (; i < n4; i += stride) {
        float4 v = reinterpret_cast<const float4*>(src)[i];
        ushort4 o;
        o.x = f2bf(v.x); o.y = f2bf(v.y); o.z = f2bf(v.z); o.w = f2bf(v.w);
        reinterpret_cast<ushort4*>(dst)[i] = o;
    }
}

// cast LoRA-A [B][16][HID] fp32 -> slice of Acat [B][48][HID] bf16
__global__ void cast_lora_a(const float* __restrict__ src, u16* __restrict__ dst,
                            int perB4, int dstStrideU16, int n4) {
    int i = blockIdx.x * blockDim.x + threadIdx.x;
    int stride = gridDim.x * blockDim.x;
    for (; i < n4; i += stride) {
        int b = i / perB4;
        int w4 = i - b * perB4;
        float4 v = reinterpret_cast<const float4*>(src)[i];
        ushort4 o;
        o.x = f2bf(v.x); o.y = f2bf(v.y); o.z = f2bf(v.z); o.w = f2bf(v.w);
        reinterpret_cast<ushort4*>(dst + (size_t)b * dstStrideU16)[w4] = o;
    }
}

// ---------- 2. LoRA down-proj via MFMA split-K ----------
template <int NT>
__global__ __launch_bounds__(256) void lora_mfma(
        const u16* __restrict__ Xb, const u16* __restrict__ Ab, float* __restrict__ T) {
    const int N = NT * 16;
    __shared__ __attribute__((aligned(16))) u16 Xls[128 * 32];
    __shared__ __attribute__((aligned(16))) u16 Als[NT * 16 * 32];
    int tid = threadIdx.x;
    int wave = tid >> 6, lane = tid & 63;
    int quad = lane >> 4, l15 = lane & 15;
    int m0 = blockIdx.y * 128;
    int b = m0 >> 10;
    int k0base = blockIdx.x * (HIDN / 4);
    const u16* Abb = Ab + (size_t)b * N * HIDN;
    f32x4 acc[2][NT] = {};
    int r0 = tid >> 2;
    int c0 = (tid & 3) * 8;
    for (int k0 = k0base; k0 < k0base + HIDN / 4; k0 += 32) {
        *(uint4*)&Xls[r0 * 32 + c0]        = *(const uint4*)&Xb[(size_t)(m0 + r0) * HIDN + k0 + c0];
        *(uint4*)&Xls[(r0 + 64) * 32 + c0] = *(const uint4*)&Xb[(size_t)(m0 + r0 + 64) * HIDN + k0 + c0];
        if (tid < NT * 16 * 4)
            *(uint4*)&Als[r0 * 32 + c0] = *(const uint4*)&Abb[(size_t)r0 * HIDN + k0 + c0];
        __syncthreads();
        short8 xf[2], af[NT];
#pragma unroll
        for (int mi = 0; mi < 2; mi++)
            xf[mi] = *(const short8*)&Xls[(wave * 32 + mi * 16 + l15) * 32 + quad * 8];
#pragma unroll
        for (int nt = 0; nt < NT; nt++)
            af[nt] = *(const short8*)&Als[(nt * 16 + l15) * 32 + quad * 8];
#pragma unroll
        for (int mi = 0; mi < 2; mi++)
#pragma unroll
            for (int nt = 0; nt < NT; nt++)
                acc[mi][nt] = __builtin_amdgcn_mfma_f32_16x16x32_bf16(xf[mi], af[nt], acc[mi][nt], 0, 0, 0);
        __syncthreads();
    }
#pragma unroll
    for (int mi = 0; mi < 2; mi++)
#pragma unroll
        for (int nt = 0; nt < NT; nt++)
#pragma unroll
            for (int r = 0; r < 4; r++) {
                int row = m0 + wave * 32 + mi * 16 + quad * 4 + r;
                atomicAdd(&T[(size_t)row * N + nt * 16 + l15], acc[mi][nt][r]);
            }
}

// ---------- 3. fused GEMM: C = Xb*Wb^T + T*Bl^T, LoRA folded as a tail K-iteration ----------
// N-dim may span up to 3 weight sections (q|k|v) with separate Bl and T slices.
__global__ __launch_bounds__(256) void gemm_fused(
        const u16* __restrict__ Xb, const u16* __restrict__ Wb,
        const float* __restrict__ T, int tstride,
        const float* __restrict__ Bl0, const float* __restrict__ Bl1, const float* __restrict__ Bl2,
        int ns0, int ns1, int ns2, int secb0, int secb1,
        void* __restrict__ outp, int Nout, int out_f32) {
    const int K = HIDN;
    __shared__ __attribute__((aligned(16))) u16 Als[128 * 32];
    __shared__ __attribute__((aligned(16))) u16 Bls[128 * 32];
    int tid = threadIdx.x;
    int wave = tid >> 6, lane = tid & 63;
    int quad = lane >> 4, l15 = lane & 15;
    int wm = wave >> 1, wn = wave & 1;
    int m0 = blockIdx.y * 128, n0 = blockIdx.x * 128;
    int b = m0 >> 10;

    // section select (a 128-col block never crosses a boundary)
    int sec = (n0 >= secb0) + (n0 >= secb1);
    const float* Blp = (sec == 0) ? Bl0 : ((sec == 1) ? Bl1 : Bl2);
    int nsec = (sec == 0) ? ns0 : ((sec == 1) ? ns1 : ns2);
    int colbase = (sec == 0) ? 0 : ((sec == 1) ? secb0 : secb1);
    int toff = sec * 16;
    const float* BlB = Blp + (size_t)b * nsec * RR;

    f32x4 acc[4][4] = {};
    int arow = wave * 32 + (lane >> 2);
    int achunk = ((lane & 3) ^ ((lane >> 3) & 3)) * 8;
    const u16* gA0 = &Xb[(size_t)(m0 + arow) * K + achunk];
    const u16* gA1 = gA0 + (size_t)16 * K;
    const u16* gB0 = &Wb[(size_t)(n0 + arow) * K + achunk];
    const u16* gB1 = gB0 + (size_t)16 * K;
    u16* lA0 = &Als[wave * 32 * 32];
    u16* lA1 = &Als[(wave * 32 + 16) * 32];
    u16* lB0 = &Bls[wave * 32 * 32];
    u16* lB1 = &Bls[(wave * 32 + 16) * 32];
    int sel = ((l15 >> 1) & 3);

    auto compute = [&]() {
        short8 af[4], bfr[4];
#pragma unroll
        for (int mi = 0; mi < 4; mi++)
            af[mi] = *(const short8*)&Als[(wm * 64 + mi * 16 + l15) * 32 + ((quad ^ sel) * 8)];
#pragma unroll
        for (int ni = 0; ni < 4; ni++)
            bfr[ni] = *(const short8*)&Bls[(wn * 64 + ni * 16 + l15) * 32 + ((quad ^ sel) * 8)];
#pragma unroll
        for (int mi = 0; mi < 4; mi++)
#pragma unroll
            for (int ni = 0; ni < 4; ni++)
                acc[mi][ni] = __builtin_amdgcn_mfma_f32_16x16x32_bf16(af[mi], bfr[ni], acc[mi][ni], 0, 0, 0);
    };

    for (int k0 = 0; k0 < K; k0 += 32) {
        glds16(gA0 + k0, lA0);
        glds16(gA1 + k0, lA1);
        glds16(gB0 + k0, lB0);
        glds16(gB1 + k0, lB1);
        __syncthreads();
        compute();
        __syncthreads();
    }

    // LoRA tail: A-tile <- T rows (16 bf16 + 16 zeros), B-tile <- Bl rows
    {
        int r = tid >> 1;
        int s = (r >> 1) & 3;
        short8 z = {0, 0, 0, 0, 0, 0, 0, 0};
        if ((tid & 1) == 0) {
            const float* Tr = &T[(size_t)(m0 + r) * tstride + toff];
            short8 c0v, c1v;
#pragma unroll
            for (int e = 0; e < 4; e++) {
                c0v[e]     = (short)f2bf(Tr[e]);
                c0v[e + 4] = (short)f2bf(Tr[4 + e]);
                c1v[e]     = (short)f2bf(Tr[8 + e]);
                c1v[e + 4] = (short)f2bf(Tr[12 + e]);
            }
            *(short8*)&Als[r * 32 + (0 ^ s) * 8] = c0v;
            *(short8*)&Als[r * 32 + (1 ^ s) * 8] = c1v;
            *(short8*)&Als[r * 32 + (2 ^ s) * 8] = z;
            *(short8*)&Als[r * 32 + (3 ^ s) * 8] = z;
        } else {
            const float* Br = &BlB[(size_t)(n0 - colbase + r) * RR];
            short8 c0v, c1v;
#pragma unroll
            for (int e = 0; e < 4; e++) {
                c0v[e]     = (short)f2bf(Br[e]);
                c0v[e + 4] = (short)f2bf(Br[4 + e]);
                c1v[e]     = (short)f2bf(Br[8 + e]);
                c1v[e + 4] = (short)f2bf(Br[12 + e]);
            }
            *(short8*)&Bls[r * 32 + (0 ^ s) * 8] = c0v;
            *(short8*)&Bls[r * 32 + (1 ^ s) * 8] = c1v;
            *(short8*)&Bls[r * 32 + (2 ^ s) * 8] = z;
            *(short8*)&Bls[r * 32 + (3 ^ s) * 8] = z;
        }
    }
    __syncthreads();
    compute();

    // pure-store epilogue
#pragma unroll
    for (int mi = 0; mi < 4; mi++) {
#pragma unroll
        for (int r = 0; r < 4; r++) {
            int row = m0 + wm * 64 + mi * 16 + quad * 4 + r;
#pragma unroll
            for (int ni = 0; ni < 4; ni++) {
                int col = n0 + wn * 64 + ni * 16 + l15;
                float v = acc[mi][ni][r];
                if (out_f32) ((float*)outp)[(size_t)row * Nout + col] = v;
                else         ((u16*)outp)[(size_t)row * Nout + col]  = f2bf(v);
            }
        }
    }
}

// ---------- 4. RoPE in place (strided rows) ----------
__global__ void rope_kernel(u16* __restrict__ x, int lognh, int rowstride, int total) {
    int idx = blockIdx.x * 256 + threadIdx.x;
    if (idx >= total) return;
    int d = idx & 63;
    int t = idx >> 6;                      // row*nh + h
    int h = t & ((1 << lognh) - 1);
    int row = t >> lognh;
    int pos = row & (SS - 1);
    size_t base = (size_t)row * rowstride + h * DD;
    float inv = __expf(-(float)d * (9.210340371976184f / 64.0f));
    float ang = (float)pos * inv;
    float c = cosf(ang), s = sinf(ang);
    float x1 = bf2f(x[base + d]);
    float x2 = bf2f(x[base + 64 + d]);
    x[base + d]      = f2bf(x1 * c - x2 * s);
    x[base + 64 + d] = f2bf(x2 * c + x1 * s);
}

// ---------- 5. flash attention: BQ=128, BK=64, V transposed; strided Q/K/V rows ----------
#define KLD 136
#define VTLD 72
#define PLD 72
__global__ __launch_bounds__(256) void flash_kernel(
        const u16* __restrict__ Q, const u16* __restrict__ Kx, const u16* __restrict__ V,
        u16* __restrict__ Oa, int qs, int kvs) {
    __shared__ __attribute__((aligned(16))) u16 Kls[64 * KLD];
    __shared__ __attribute__((aligned(16))) u16 Vt[128 * VTLD];
    __shared__ __attribute__((aligned(16))) u16 Pls[4 * 32 * PLD];
    int tid = threadIdx.x;
    int wave = tid >> 6, lane = tid & 63;
    int quad = lane >> 4, l15 = lane & 15;
    int blk = blockIdx.x;
    int qt = 7 - (blk >> 7);
    int h  = blk & 31;
    int b  = (blk >> 5) & 3;
    int hkv = h >> 2;
    int q0 = qt * 128;
    const float scale = 0.08838834764831845f;

    short8 qf[2][4];
#pragma unroll
    for (int mi = 0; mi < 2; mi++) {
        int qrow = q0 + (wave + 4 * mi) * 16 + l15;
        const u16* qp = Q + (size_t)(b * SS + qrow) * qs + h * DD;
#pragma unroll
        for (int kt = 0; kt < 4; kt++) qf[mi][kt] = *(const short8*)&qp[kt * 32 + quad * 8];
    }

    f32x4 oacc[2][8] = {};
    float mrow[2][4], lrow[2][4];
#pragma unroll
    for (int mi = 0; mi < 2; mi++)
#pragma unroll
        for (int r = 0; r < 4; r++) { mrow[mi][r] = -3.0e38f; lrow[mi][r] = 0.f; }

    int krow = tid >> 2;
    int kc   = (tid & 3) * 32;
    int vp   = tid >> 3;
    int vc   = (tid & 7) * 16;

    int nkb = (q0 >> 6) + 2;
    for (int ib = 0; ib < nkb; ib++) {
        int kb = ib * 64;
        const u16* kg = Kx + (size_t)(b * SS + kb + krow) * kvs + hkv * DD + kc;
#pragma unroll
        for (int j = 0; j < 4; j++)
            *(uint4*)&Kls[krow * KLD + kc + j * 8] = *(const uint4*)&kg[j * 8];
        const u16* vg0 = V + (size_t)(b * SS + kb + 2 * vp) * kvs + hkv * DD + vc;
        const u16* vg1 = vg0 + kvs;
#pragma unroll
        for (int j = 0; j < 2; j++) {
            uint4 a4 = *(const uint4*)&vg0[j * 8];
            uint4 b4 = *(const uint4*)&vg1[j * 8];
            const u16* ap = (const u16*)&a4;
            const u16* bp = (const u16*)&b4;
#pragma unroll
            for (int e = 0; e < 8; e++) {
                unsigned pk = (unsigned)ap[e] | ((unsigned)bp[e] << 16);
                *(unsigned*)&Vt[(size_t)(vc + j * 8 + e) * VTLD + 2 * vp] = pk;
            }
        }
        __syncthreads();

        f32x4 sa[2][4] = {};
#pragma unroll
        for (int nt = 0; nt < 4; nt++) {
            short8 kf[4];
#pragma unroll
            for (int kt = 0; kt < 4; kt++)
                kf[kt] = *(const short8*)&Kls[(nt * 16 + l15) * KLD + kt * 32 + quad * 8];
#pragma unroll
            for (int mi = 0; mi < 2; mi++)
#pragma unroll
                for (int kt = 0; kt < 4; kt++)
                    sa[mi][nt] = __builtin_amdgcn_mfma_f32_16x16x32_bf16(qf[mi][kt], kf[kt], sa[mi][nt], 0, 0, 0);
        }

#pragma unroll
        for (int mi = 0; mi < 2; mi++) {
#pragma unroll
            for (int r = 0; r < 4; r++) {
                int qpos = q0 + (wave + 4 * mi) * 16 + quad * 4 + r;
                float s[4];
#pragma unroll
                for (int nt = 0; nt < 4; nt++) {
                    float v = sa[mi][nt][r] * scale;
                    int kpos = kb + nt * 16 + l15;
                    s[nt] = (kpos > qpos) ? -3.0e38f : v;
                }
                float mx = fmaxf(fmaxf(s[0], s[1]), fmaxf(s[2], s[3]));
#pragma unroll
                for (int off = 1; off < 16; off <<= 1) mx = fmaxf(mx, __shfl_xor(mx, off, 64));
                float mnew = fmaxf(mrow[mi][r], mx);
                float alpha = __expf(mrow[mi][r] - mnew);
                mrow[mi][r] = mnew;
                float sum = 0.f;
#pragma unroll
                for (int nt = 0; nt < 4; nt++) {
                    float e = __expf(s[nt] - mnew);
                    sum += e;
                    Pls[wave * (32 * PLD) + (mi * 16 + quad * 4 + r) * PLD + nt * 16 + l15] = f2bf(e);
                }
#pragma unroll
                for (int off = 1; off < 16; off <<= 1) sum += __shfl_xor(sum, off, 64);
                lrow[mi][r] = lrow[mi][r] * alpha + sum;
#pragma unroll
                for (int dt = 0; dt < 8; dt++) oacc[mi][dt][r] *= alpha;
            }
        }
        __syncthreads();

#pragma unroll
        for (int kt = 0; kt < 2; kt++) {
            short8 pf[2];
#pragma unroll
            for (int mi = 0; mi < 2; mi++)
                pf[mi] = *(const short8*)&Pls[wave * (32 * PLD) + (mi * 16 + l15) * PLD + kt * 32 + quad * 8];
#pragma unroll
            for (int dt = 0; dt < 8; dt++) {
                short8 vf = *(const short8*)&Vt[(size_t)(dt * 16 + l15) * VTLD + kt * 32 + quad * 8];
#pragma unroll
                for (int mi = 0; mi < 2; mi++)
                    oacc[mi][dt] = __builtin_amdgcn_mfma_f32_16x16x32_bf16(pf[mi], vf, oacc[mi][dt], 0, 0, 0);
            }
        }
        __syncthreads();
    }

#pragma unroll
    for (int mi = 0; mi < 2; mi++)
#pragma unroll
        for (int r = 0; r < 4; r++) {
            float inv = 1.0f / lrow[mi][r];
            int orow = q0 + (wave + 4 * mi) * 16 + quad * 4 + r;
            u16* op = Oa + ((size_t)(b * SS + orow) * HH + h) * DD;
#pragma unroll
            for (int dt = 0; dt < 8; dt++)
                op[dt * 16 + l15] = f2bf(oacc[mi][dt][r] * inv);
        }
}

// ---------- launch ----------
extern "C" void kernel_launch(void* const* d_in, const int* in_sizes, int n_in,
                              void* d_out, int out_size, void* d_ws, size_t ws_size,
                              hipStream_t stream) {
    const float* X  = (const float*)d_in[0];
    const float* Wq = (const float*)d_in[1];
    const float* Wk = (const float*)d_in[2];
    const float* Wv = (const float*)d_in[3];
    const float* Wo = (const float*)d_in[4];
    const float* Aq = (const float*)d_in[5];
    const float* Bq = (const float*)d_in[6];
    const float* Ak = (const float*)d_in[7];
    const float* Bk = (const float*)d_in[8];
    const float* Av = (const float*)d_in[9];
    const float* Bv = (const float*)d_in[10];
    const float* Ao = (const float*)d_in[11];
    const float* Bo = (const float*)d_in[12];

    char* w = (char*)d_ws;
    auto take = [&](size_t bytes) {
        char* p = w;
        w += (bytes + 255) & ~(size_t)255;
        return p;
    };
    u16*   Xb  = (u16*)  take((size_t)MM * HIDN * 2);
    u16*   Wqb = (u16*)  take((size_t)HIDN * HIDN * 2);     // Wq|Wk|Wv contiguous (sizes are 256B multiples)
    u16*   Wkb = (u16*)  take((size_t)1024 * HIDN * 2);
    u16*   Wvb = (u16*)  take((size_t)1024 * HIDN * 2);
    u16*   Wob = (u16*)  take((size_t)HIDN * HIDN * 2);
    float* Tcat= (float*)take((size_t)MM * 48 * 4);          // q|k|v lora-down, [M][48]
    float* To  = (float*)take((size_t)MM * 16 * 4);          // o lora-down, [M][16]
    u16*   Acat= (u16*)  take((size_t)BB * 48 * HIDN * 2);
    u16*   Aob = (u16*)  take((size_t)BB * 16 * HIDN * 2);
    u16*   qkv = (u16*)  take((size_t)MM * NQKV * 2);        // [M][6144] = q|k|v packed
    u16*   attn = Xb;   // Xb dead after QKV GEMM

    (void)Wkb; (void)Wvb;

    zero_kernel<<<(MM * 64 + 255) / 256, 256, 0, stream>>>(Tcat, MM * 64);

    cast_kernel<<<2048, 256, 0, stream>>>(X,  Xb,  MM * HIDN / 4);
    cast_kernel<<<2048, 256, 0, stream>>>(Wq, Wqb, HIDN * HIDN / 4);
    cast_kernel<<<1024, 256, 0, stream>>>(Wk, Wkb, 1024 * HIDN / 4);
    cast_kernel<<<1024, 256, 0, stream>>>(Wv, Wvb, 1024 * HIDN / 4);
    cast_kernel<<<2048, 256, 0, stream>>>(Wo, Wob, HIDN * HIDN / 4);
    {
        const int perB4 = 16 * HIDN / 4;
        const int n4 = BB * perB4;
        cast_lora_a<<<256, 256, 0, stream>>>(Aq, Acat,             perB4, 48 * HIDN, n4);
        cast_lora_a<<<256, 256, 0, stream>>>(Ak, Acat + 16 * HIDN, perB4, 48 * HIDN, n4);
        cast_lora_a<<<256, 256, 0, stream>>>(Av, Acat + 32 * HIDN, perB4, 48 * HIDN, n4);
        cast_kernel<<<256, 256, 0, stream>>>(Ao, Aob, BB * 16 * HIDN / 4);
    }

    lora_mfma<3><<<dim3(4, 32), 256, 0, stream>>>(Xb, Acat, Tcat);

    // fused Q|K|V projection GEMM, N=6144, LoRA folded into tail K-iteration
    gemm_fused<<<dim3(48, 32), 256, 0, stream>>>(
        Xb, Wqb, Tcat, 48, Bq, Bk, Bv, HIDN, 1024, 1024, 4096, 5120,
        (void*)qkv, NQKV, 0);

    rope_kernel<<<(BB * SS * HH * 64 + 255) / 256, 256, 0, stream>>>(qkv,        5, NQKV, BB * SS * HH * 64);
    rope_kernel<<<(BB * SS * HKV * 64 + 255) / 256, 256, 0, stream>>>(qkv + 4096, 3, NQKV, BB * SS * HKV * 64);

    flash_kernel<<<BB * HH * (SS / 128), 256, 0, stream>>>(qkv, qkv + 4096, qkv + 5120, attn, NQKV, NQKV);

    lora_mfma<1><<<dim3(4, 32), 256, 0, stream>>>(attn, Aob, To);

    // O projection GEMM (single section), fp32 out
    gemm_fused<<<dim3(32, 32), 256, 0, stream>>>(
        attn, Wob, To, 16, Bo, Bo, Bo, HIDN, HIDN, HIDN, 1 << 30, 1 << 30,
        (void*)d_out, HIDN, 1);
}